// Round 8
// baseline (34.681 us; speedup 1.0000x reference)
//
#include <hip/hip_runtime.h>
#include <math.h>

// B=32, S=1024, D=256, V=50000.
// loss(b,s) = log S(k) - 0.98*k - 0.1*dot - 344.3348757
//   k = ||preds[b,:,s]||, dot = <emb[target], preds[b,:,s]>
//   S = 0F1(;128;k^2/4) = 1 + sum_{j>=1} prod_{i<j} (k^2/4)/((i+1)(128+i))
// (exact rewrite of -logcmk(256,k) - 0.1 dot + 0.02 k; verified absmax 0.0)
// out = sum(loss*mask)/sum(mask), mask = target != 1.
//
// Single fused kernel: per-block partials stored with agent-scope atomic
// stores (coherent point, no fences), one ACQ_REL counter increment per
// block, last block reduces 2*512 partials and writes out[0]. Counter is
// zeroed by a 4-byte memset node captured in the graph.

constexpr int Dc = 256;
constexpr int Sc = 1024;
constexpr int Bc = 32;
constexpr int TILE = 64;                  // positions per block
constexpr int NBLK = Bc * Sc / TILE;      // 512
constexpr int NW   = 8;                   // waves per block (512 threads)

using f4 = __attribute__((ext_vector_type(4))) float;

__global__ __launch_bounds__(512, 4) void nllvmf_fused(
    const float* __restrict__ preds,
    const float* __restrict__ emb,
    const int*   __restrict__ target,
    float*       __restrict__ out,
    float*       __restrict__ ws)   // [0..NBLK) loss, [NBLK..2N) mask, [2N] counter
{
    __shared__ float s_r[NW][2][64];      // [wave][n2|dot][pos]
    __shared__ int s_last;

    const int tid = threadIdx.x;
    const int blk = blockIdx.x;
    const int b   = blk >> 4;             // Sc/TILE = 16 blocks per batch row
    const int s0  = (blk & 15) * TILE;
    const int w   = tid >> 6;             // wave: dim slice w*32 .. w*32+31
    const int l   = tid & 63;
    const int td  = l >> 3;               // 8 dim-groups of 4 dims
    const int sg  = l & 7;                // 8 position-groups
    const int d0  = w * 32 + td * 4;
    const int p0  = s0 + sg * 4;          // chunk c=0: p0..p0+3, c=1: p0+32..p0+35

    // targets for this thread's 8 positions (two int4, both 16B-aligned)
    const int4 tA = *reinterpret_cast<const int4*>(target + b * Sc + p0);
    const int4 tB = *reinterpret_cast<const int4*>(target + b * Sc + p0 + 32);
    const int tg[8] = {tA.x, tA.y, tA.z, tA.w, tB.x, tB.y, tB.z, tB.w};

    // 8 preds float4 (plain loads: 85 MB total footprint is L3-resident
    // across graph replays; nt would force HBM re-fetch every replay).
    // Per td-group each instruction covers 128B fully-contiguous, fully used.
    const float* pb = preds + (size_t)b * Dc * Sc + (size_t)d0 * Sc + p0;
    f4 p[4][2];
    #pragma unroll
    for (int q = 0; q < 4; ++q) {
        p[q][0] = *reinterpret_cast<const f4*>(pb + (size_t)q * Sc);
        p[q][1] = *reinterpret_cast<const f4*>(pb + (size_t)q * Sc + 32);
    }
    // 8 emb gathers
    f4 e[8];
    #pragma unroll
    for (int j = 0; j < 8; ++j)
        e[j] = *reinterpret_cast<const f4*>(emb + (size_t)tg[j] * Dc + d0);

    float n2[8] = {0,0,0,0,0,0,0,0};
    float dt[8] = {0,0,0,0,0,0,0,0};
    #pragma unroll
    for (int q = 0; q < 4; ++q)
        #pragma unroll
        for (int j = 0; j < 8; ++j) {
            const float pv = p[q][j >> 2][j & 3];
            n2[j] = fmaf(pv, pv, n2[j]);
            dt[j] = fmaf(pv, e[j][q], dt[j]);
        }

    // butterfly over td (lane bits 3..5): sum this wave's 32 dims
    #pragma unroll
    for (int m = 8; m <= 32; m <<= 1)
        #pragma unroll
        for (int j = 0; j < 8; ++j) {
            n2[j] += __shfl_xor(n2[j], m, 64);
            dt[j] += __shfl_xor(dt[j], m, 64);
        }

    if (td == 0) {
        #pragma unroll
        for (int j = 0; j < 8; ++j) {
            const int pos = (j >> 2) * 32 + sg * 4 + (j & 3);
            s_r[w][0][pos] = n2[j];
            s_r[w][1][pos] = dt[j];
        }
    }
    __syncthreads();

    if (tid < 64) {
        float norm2 = 0.f, dot = 0.f;
        #pragma unroll
        for (int w2 = 0; w2 < NW; ++w2) {
            norm2 += s_r[w2][0][tid];
            dot   += s_r[w2][1][tid];
        }
        const int tgt = target[b * Sc + s0 + tid];

        const float k = sqrtf(norm2);
        const float r = 0.25f * norm2;

        // S = 0F1(;128;r), 32-term recurrence; reciprocals are literals
        constexpr float INV[32] = {
            1.0f/128.0f,  1.0f/258.0f,  1.0f/390.0f,  1.0f/524.0f,
            1.0f/660.0f,  1.0f/798.0f,  1.0f/938.0f,  1.0f/1080.0f,
            1.0f/1224.0f, 1.0f/1370.0f, 1.0f/1518.0f, 1.0f/1668.0f,
            1.0f/1820.0f, 1.0f/1974.0f, 1.0f/2130.0f, 1.0f/2288.0f,
            1.0f/2448.0f, 1.0f/2610.0f, 1.0f/2774.0f, 1.0f/2940.0f,
            1.0f/3108.0f, 1.0f/3278.0f, 1.0f/3450.0f, 1.0f/3624.0f,
            1.0f/3800.0f, 1.0f/3978.0f, 1.0f/4158.0f, 1.0f/4340.0f,
            1.0f/4524.0f, 1.0f/4710.0f, 1.0f/4898.0f, 1.0f/5088.0f };
        float t = 1.0f, S = 1.0f;
        #pragma unroll
        for (int j = 0; j < 32; ++j) { t *= r * INV[j]; S += t; }

        float loss = __logf(S) - 0.98f * k - 0.1f * dot - 344.3348757f;
        float msk  = (tgt != 1) ? 1.0f : 0.0f;
        loss *= msk;

        #pragma unroll
        for (int m = 32; m; m >>= 1) {
            loss += __shfl_xor(loss, m, 64);
            msk  += __shfl_xor(msk,  m, 64);
        }
        if (tid == 0) {
            // agent-scope atomic stores: visible device-wide without fences
            __hip_atomic_store(&ws[blk],        loss, __ATOMIC_RELAXED, __HIP_MEMORY_SCOPE_AGENT);
            __hip_atomic_store(&ws[NBLK + blk], msk,  __ATOMIC_RELAXED, __HIP_MEMORY_SCOPE_AGENT);
            unsigned prev = __hip_atomic_fetch_add(
                (unsigned*)(ws + 2 * NBLK), 1u, __ATOMIC_ACQ_REL, __HIP_MEMORY_SCOPE_AGENT);
            s_last = (prev == (unsigned)(NBLK - 1));
        }
    }
    __syncthreads();

    if (s_last && tid < 64) {
        float lsum = 0.f, msum = 0.f;
        #pragma unroll
        for (int i = tid; i < NBLK; i += 64) {
            lsum += __hip_atomic_load(&ws[i],        __ATOMIC_RELAXED, __HIP_MEMORY_SCOPE_AGENT);
            msum += __hip_atomic_load(&ws[NBLK + i], __ATOMIC_RELAXED, __HIP_MEMORY_SCOPE_AGENT);
        }
        #pragma unroll
        for (int m = 32; m; m >>= 1) {
            lsum += __shfl_xor(lsum, m, 64);
            msum += __shfl_xor(msum, m, 64);
        }
        if (tid == 0) out[0] = lsum / msum;
    }
}

extern "C" void kernel_launch(void* const* d_in, const int* in_sizes, int n_in,
                              void* d_out, int out_size, void* d_ws, size_t ws_size,
                              hipStream_t stream) {
    const float* preds  = (const float*)d_in[0];
    const float* emb    = (const float*)d_in[1];
    const int*   target = (const int*)d_in[2];
    float* out = (float*)d_out;
    float* ws  = (float*)d_ws;

    // zero only the completion counter (4 bytes) each call
    hipMemsetAsync(ws + 2 * NBLK, 0, sizeof(unsigned), stream);
    nllvmf_fused<<<NBLK, 512, 0, stream>>>(preds, emb, target, out, ws);
}

// Round 9
// 17.375 us; speedup vs baseline: 1.9960x; 1.9960x over previous
//
#include <hip/hip_runtime.h>
#include <math.h>

// B=32, S=1024, D=256, V=50000.
// loss(b,s) = log S(k) - 0.98*k - 0.1*dot - 344.3348757
//   k = ||preds[b,:,s]||, dot = <emb[target], preds[b,:,s]>
//   S = 0F1(;128;k^2/4) = 1 + sum_{j>=1} prod_{i<j} (k^2/4)/((i+1)(128+i))
// (exact rewrite of -logcmk(256,k) - 0.1 dot + 0.02 k; verified absmax 0.0)
// out = sum(loss*mask)/sum(mask), mask = target != 1.
//
// Structure (R7 + VGPR diet): two kernels, per-block partial stores (no
// cross-block atomics — proven toxic in R3/R8). emb gathers batched 4+4 to
// cut live VGPRs; __launch_bounds__(512,6) targets 24 waves/CU.

constexpr int Dc = 256;
constexpr int Sc = 1024;
constexpr int Bc = 32;
constexpr int TILE = 64;                  // positions per block
constexpr int NBLK = Bc * Sc / TILE;      // 512
constexpr int NW   = 8;                   // waves per block (512 threads)

using f4 = __attribute__((ext_vector_type(4))) float;

__global__ __launch_bounds__(512, 6) void nllvmf_main(
    const float* __restrict__ preds,
    const float* __restrict__ emb,
    const int*   __restrict__ target,
    float*       __restrict__ partial)    // [0..NBLK): loss, [NBLK..2N): mask
{
    __shared__ float s_r[NW][2][64];      // [wave][n2|dot][pos]

    const int tid = threadIdx.x;
    const int blk = blockIdx.x;
    const int b   = blk >> 4;             // Sc/TILE = 16 blocks per batch row
    const int s0  = (blk & 15) * TILE;
    const int w   = tid >> 6;             // wave: dim slice w*32 .. w*32+31
    const int l   = tid & 63;
    const int td  = l >> 3;               // 8 dim-groups of 4 dims
    const int sg  = l & 7;                // 8 position-groups
    const int d0  = w * 32 + td * 4;
    const int p0  = s0 + sg * 4;          // chunk c=0: p0..p0+3, c=1: p0+32..p0+35

    // targets for this thread's 8 positions (two int4, both 16B-aligned)
    const int4 tA = *reinterpret_cast<const int4*>(target + b * Sc + p0);
    const int4 tB = *reinterpret_cast<const int4*>(target + b * Sc + p0 + 32);

    // 8 preds float4, non-temporal (read-once stream, full HBM latency ->
    // keep all 8 in flight). Per td-group each instruction covers 128B
    // fully-contiguous, fully used.
    const float* pb = preds + (size_t)b * Dc * Sc + (size_t)d0 * Sc + p0;
    f4 p[4][2];
    #pragma unroll
    for (int q = 0; q < 4; ++q) {
        p[q][0] = __builtin_nontemporal_load(reinterpret_cast<const f4*>(pb + (size_t)q * Sc));
        p[q][1] = __builtin_nontemporal_load(reinterpret_cast<const f4*>(pb + (size_t)q * Sc + 32));
    }

    float n2[8] = {0,0,0,0,0,0,0,0};
    float dt[8] = {0,0,0,0,0,0,0,0};

    // emb gathers in two batches of 4 (halves live e-registers; emb is
    // L2/L3-resident so the exposed second batch is short and hidden by
    // the extra waves the lower VGPR count buys).
    {
        const int tgA[4] = {tA.x, tA.y, tA.z, tA.w};
        f4 e[4];
        #pragma unroll
        for (int j = 0; j < 4; ++j)
            e[j] = *reinterpret_cast<const f4*>(emb + (size_t)tgA[j] * Dc + d0);
        #pragma unroll
        for (int q = 0; q < 4; ++q)
            #pragma unroll
            for (int j = 0; j < 4; ++j) {
                const float pv = p[q][0][j];
                n2[j] = fmaf(pv, pv, n2[j]);
                dt[j] = fmaf(pv, e[j][q], dt[j]);
            }
    }
    {
        const int tgB[4] = {tB.x, tB.y, tB.z, tB.w};
        f4 e[4];
        #pragma unroll
        for (int j = 0; j < 4; ++j)
            e[j] = *reinterpret_cast<const f4*>(emb + (size_t)tgB[j] * Dc + d0);
        #pragma unroll
        for (int q = 0; q < 4; ++q)
            #pragma unroll
            for (int j = 0; j < 4; ++j) {
                const float pv = p[q][1][j];
                n2[4 + j] = fmaf(pv, pv, n2[4 + j]);
                dt[4 + j] = fmaf(pv, e[j][q], dt[4 + j]);
            }
    }

    // butterfly over td (lane bits 3..5): sum this wave's 32 dims
    #pragma unroll
    for (int m = 8; m <= 32; m <<= 1)
        #pragma unroll
        for (int j = 0; j < 8; ++j) {
            n2[j] += __shfl_xor(n2[j], m, 64);
            dt[j] += __shfl_xor(dt[j], m, 64);
        }

    if (td == 0) {
        #pragma unroll
        for (int j = 0; j < 8; ++j) {
            const int pos = (j >> 2) * 32 + sg * 4 + (j & 3);
            s_r[w][0][pos] = n2[j];
            s_r[w][1][pos] = dt[j];
        }
    }
    __syncthreads();

    if (tid < 64) {
        float norm2 = 0.f, dot = 0.f;
        #pragma unroll
        for (int w2 = 0; w2 < NW; ++w2) {
            norm2 += s_r[w2][0][tid];
            dot   += s_r[w2][1][tid];
        }
        const int tgt = target[b * Sc + s0 + tid];

        const float k = sqrtf(norm2);
        const float r = 0.25f * norm2;

        // S = 0F1(;128;r), 32-term recurrence; reciprocals are literals
        constexpr float INV[32] = {
            1.0f/128.0f,  1.0f/258.0f,  1.0f/390.0f,  1.0f/524.0f,
            1.0f/660.0f,  1.0f/798.0f,  1.0f/938.0f,  1.0f/1080.0f,
            1.0f/1224.0f, 1.0f/1370.0f, 1.0f/1518.0f, 1.0f/1668.0f,
            1.0f/1820.0f, 1.0f/1974.0f, 1.0f/2130.0f, 1.0f/2288.0f,
            1.0f/2448.0f, 1.0f/2610.0f, 1.0f/2774.0f, 1.0f/2940.0f,
            1.0f/3108.0f, 1.0f/3278.0f, 1.0f/3450.0f, 1.0f/3624.0f,
            1.0f/3800.0f, 1.0f/3978.0f, 1.0f/4158.0f, 1.0f/4340.0f,
            1.0f/4524.0f, 1.0f/4710.0f, 1.0f/4898.0f, 1.0f/5088.0f };
        float t = 1.0f, S = 1.0f;
        #pragma unroll
        for (int j = 0; j < 32; ++j) { t *= r * INV[j]; S += t; }

        float loss = __logf(S) - 0.98f * k - 0.1f * dot - 344.3348757f;
        float msk  = (tgt != 1) ? 1.0f : 0.0f;
        loss *= msk;

        #pragma unroll
        for (int m = 32; m; m >>= 1) {
            loss += __shfl_xor(loss, m, 64);
            msk  += __shfl_xor(msk,  m, 64);
        }
        if (tid == 0) {
            partial[blk]        = loss;
            partial[NBLK + blk] = msk;
        }
    }
}

__global__ __launch_bounds__(128) void nllvmf_finalize(
    const float* __restrict__ partial, float* __restrict__ out)
{
    __shared__ float sl[2], sm[2];
    const int tid = threadIdx.x;
    f4 lv = *reinterpret_cast<const f4*>(partial + tid * 4);
    f4 mv = *reinterpret_cast<const f4*>(partial + NBLK + tid * 4);
    float l = lv.x + lv.y + lv.z + lv.w;
    float m = mv.x + mv.y + mv.z + mv.w;
    #pragma unroll
    for (int off = 32; off; off >>= 1) {
        l += __shfl_down(l, off, 64);
        m += __shfl_down(m, off, 64);
    }
    if ((tid & 63) == 0) { sl[tid >> 6] = l; sm[tid >> 6] = m; }
    __syncthreads();
    if (tid == 0)
        out[0] = (sl[0] + sl[1]) / (sm[0] + sm[1]);
}

extern "C" void kernel_launch(void* const* d_in, const int* in_sizes, int n_in,
                              void* d_out, int out_size, void* d_ws, size_t ws_size,
                              hipStream_t stream) {
    const float* preds  = (const float*)d_in[0];
    const float* emb    = (const float*)d_in[1];
    const int*   target = (const int*)d_in[2];
    float* out = (float*)d_out;
    float* ws  = (float*)d_ws;

    nllvmf_main<<<NBLK, 512, 0, stream>>>(preds, emb, target, ws);
    nllvmf_finalize<<<1, 128, 0, stream>>>(ws, out);
}